// Round 17
// baseline (167.461 us; speedup 1.0000x reference)
//
#include <hip/hip_runtime.h>
#include <hip/hip_bf16.h>
#include <math.h>

#define D_MODEL 1024
#define N_HEAD  16
#define HD      64
#define B_SZ    4
#define T_SEQ   2048
#define M_TOT   (B_SZ * T_SEQ)   // 8192
#define N_TOT   (3 * D_MODEL)    // 3072

typedef __bf16 bf16_t;
typedef __bf16 bf16x8 __attribute__((ext_vector_type(8)));
typedef __bf16 bf16x4 __attribute__((ext_vector_type(4)));
typedef __bf16 bf16x2 __attribute__((ext_vector_type(2)));
typedef float  f32x4  __attribute__((ext_vector_type(4)));
typedef float  f32x16 __attribute__((ext_vector_type(16)));
typedef int    i32x4  __attribute__((ext_vector_type(4)));

// softmax scale folded with log2(e): scores end up in log2 domain -> exp2
#define Q_PRESCALE 0.18033688011112042f   // (1/8) * log2(e)

// raw v_exp_f32 (2^x): single instruction (r15 win).
__device__ inline float fexp2(float x) { return __builtin_amdgcn_exp2f(x); }

// ---------------- fused fp32 -> bf16 conversion (both inputs, one launch) ----------------
__global__ __launch_bounds__(256) void cvt_both(const float* __restrict__ x,
                                                bf16_t* __restrict__ xb, int n4x,
                                                const float* __restrict__ W,
                                                bf16_t* __restrict__ wb, int n4w) {
  int i = blockIdx.x * blockDim.x + threadIdx.x;
  int stride = gridDim.x * blockDim.x;
  const int ntot = n4x + n4w;
  for (; i < ntot; i += stride) {
    const float4* src = (i < n4x) ? &((const float4*)x)[i] : &((const float4*)W)[i - n4x];
    bf16x4* dst = (i < n4x) ? &((bf16x4*)xb)[i] : &((bf16x4*)wb)[i - n4x];
    float4 v = *src;
    bf16x4 o;
    o[0] = (bf16_t)v.x; o[1] = (bf16_t)v.y; o[2] = (bf16_t)v.z; o[3] = (bf16_t)v.w;
    *dst = o;
  }
}

// ---------------- QKV projection GEMM (bf16 MFMA, 128x128 tile) ----------------
// REVERTED to r15-exact (70us, best measured; r16's 256x128 regressed to 73.5).
// 3-buf counted-vmcnt pipeline + pre-swizzled staging + packed/LDS-transpose
// epilogue.
//  Kf[bh][t>>5][d>>4][(d>>3)&1][t&31][d&7]
//  Vf[bh][t>>5][(d>>5)*2+((t&31)>>4)][((t&31)>>3)&1][d&31][t&7]
__global__ __launch_bounds__(256) void qkv_gemm(const bf16_t* __restrict__ xb,
                                                const bf16_t* __restrict__ wb,
                                                bf16_t* __restrict__ Q,
                                                bf16_t* __restrict__ Kf,
                                                bf16_t* __restrict__ Vf) {
  __shared__ alignas(16) bf16_t smem[24576];   // 48 KB: staging; aliased as C-tile in epilogue
  bf16_t* a_lds = smem;                        // [3][4096]
  bf16_t* b_lds = smem + 12288;                // [3][4096]
  bf16_t* c_lds = smem;                        // [128][132] bf16 — epilogue only

  const int tid  = threadIdx.x;
  const int wave = tid >> 6;
  const int lane = tid & 63;
  const int bm = blockIdx.y * 128;
  const int bn = blockIdx.x * 128;
  const int sec = bn >> 10;                    // whole block in one section

  f32x4 acc[4][4] = {};

  const int sRow  = lane >> 2;
  const int sCol8 = (lane & 3) ^ ((lane >> 3) & 3);   // pre-swizzled global col8
  const int fr = lane & 15;
  const int fk = lane >> 4;
  const int wm = (wave >> 1) * 64;
  const int wn = (wave & 1) * 64;

  auto stage = [&](int buf, int kk) {
#pragma unroll
    for (int c = 0; c < 2; ++c) {
      const int chunk = wave * 2 + c;
      const bf16_t* gA = &xb[(size_t)(bm + chunk * 16 + sRow) * D_MODEL + kk + sCol8 * 8];
      __builtin_amdgcn_global_load_lds(
          (__attribute__((address_space(1))) void*)(void*)gA,
          (__attribute__((address_space(3))) void*)&a_lds[buf * 4096 + chunk * 512], 16, 0, 0);
      const bf16_t* gB = &wb[(size_t)(bn + chunk * 16 + sRow) * D_MODEL + kk + sCol8 * 8];
      __builtin_amdgcn_global_load_lds(
          (__attribute__((address_space(1))) void*)(void*)gB,
          (__attribute__((address_space(3))) void*)&b_lds[buf * 4096 + chunk * 512], 16, 0, 0);
    }
  };

  auto loadFrags = [&](int buf, bf16x8 af[4], bf16x8 bfr[4]) {
#pragma unroll
    for (int mt = 0; mt < 4; ++mt) {
      const int row = wm + mt * 16 + fr;
      af[mt] = *(const bf16x8*)&a_lds[buf * 4096 + row * 32 + (fk ^ ((fr >> 1) & 3)) * 8];
    }
#pragma unroll
    for (int nt = 0; nt < 4; ++nt) {
      const int row = wn + nt * 16 + fr;
      bfr[nt] = *(const bf16x8*)&b_lds[buf * 4096 + row * 32 + (fk ^ ((fr >> 1) & 3)) * 8];
    }
  };

  auto mfmaAll = [&](bf16x8 af[4], bf16x8 bfr[4]) {
    __builtin_amdgcn_s_setprio(1);
#pragma unroll
    for (int mt = 0; mt < 4; ++mt)
#pragma unroll
      for (int nt = 0; nt < 4; ++nt)
        acc[mt][nt] = __builtin_amdgcn_mfma_f32_16x16x32_bf16(af[mt], bfr[nt], acc[mt][nt], 0, 0, 0);
    __builtin_amdgcn_s_setprio(0);
  };

  stage(0, 0);
  stage(1, 32);
  int cur = 0;
  for (int t = 0; t < 31; ++t) {
    asm volatile("s_waitcnt vmcnt(4)" ::: "memory");
    __builtin_amdgcn_s_barrier();
    __builtin_amdgcn_sched_barrier(0);
    bf16x8 af[4], bfr[4];
    loadFrags(cur, af, bfr);
    if (t < 30) stage((t + 2) % 3, (t + 2) * 32);
    mfmaAll(af, bfr);
    cur = (cur + 1) % 3;
  }
  asm volatile("s_waitcnt vmcnt(0)" ::: "memory");
  __builtin_amdgcn_s_barrier();
  __builtin_amdgcn_sched_barrier(0);
  {
    bf16x8 af[4], bfr[4];
    loadFrags(cur, af, bfr);
    mfmaAll(af, bfr);
  }

  const int cRowBase = (lane >> 4) * 4;
  const int cCol     = lane & 15;

  if (sec == 2) {
    // ---- V: direct packed 8B stores ----
#pragma unroll
    for (int mt = 0; mt < 4; ++mt) {
#pragma unroll
      for (int nt = 0; nt < 4; ++nt) {
        const int hn = (bn & 1023) + wn + nt * 16 + cCol;
        const int h  = hn >> 6;
        const int d  = hn & 63;
        const int mbase = bm + wm + mt * 16 + cRowBase;
        const int b  = mbase >> 11;
        const int t0 = mbase & 2047;
        const int kvt = t0 >> 5, tt0 = t0 & 31;
        const int idx = (d >> 5) * 2 + (tt0 >> 4);
        const int h2  = (tt0 >> 3) & 1;
        const int j0  = tt0 & 7;
        bf16x4 pk;
        pk[0] = (bf16_t)acc[mt][nt][0]; pk[1] = (bf16_t)acc[mt][nt][1];
        pk[2] = (bf16_t)acc[mt][nt][2]; pk[3] = (bf16_t)acc[mt][nt][3];
        const size_t bhOff = (size_t)(b * N_HEAD + h) * (T_SEQ * HD);
        *(bf16x4*)&Vf[bhOff + (size_t)(((kvt * 4 + idx) * 64 + h2 * 32 + (d & 31)) * 8 + j0)] = pk;
      }
    }
  } else {
    // ---- Q/K: LDS transpose then contiguous 8B stores ----
    __syncthreads();
    const float qs = (sec == 0) ? Q_PRESCALE : 1.0f;
#pragma unroll
    for (int mt = 0; mt < 4; ++mt)
#pragma unroll
      for (int nt = 0; nt < 4; ++nt)
#pragma unroll
        for (int r = 0; r < 4; ++r) {
          const int mloc = wm + mt * 16 + cRowBase + r;
          const int nloc = wn + nt * 16 + cCol;
          c_lds[mloc * 132 + nloc] = (bf16_t)(acc[mt][nt][r] * qs);
        }
    __syncthreads();

    const int row = tid >> 1;
    const int nh  = tid & 1;
    const int m = bm + row;
    const int b = m >> 11, t = m & 2047;
    const int h = ((bn & 1023) + nh * 64) >> 6;
    const size_t bhOff = (size_t)(b * N_HEAD + h) * (T_SEQ * HD);

    if (sec == 0) {
      bf16_t* qp = Q + bhOff + (size_t)t * HD;
#pragma unroll
      for (int o = 0; o < 16; ++o) {
        bf16x4 vv = *(const bf16x4*)&c_lds[row * 132 + nh * 64 + o * 4];
        *(bf16x4*)&qp[o * 4] = vv;
      }
    } else {
      const int kvt = t >> 5, lk = t & 31;
#pragma unroll
      for (int o = 0; o < 16; ++o) {
        const int d0 = o * 4;
        const int cc = d0 >> 4, h2 = (d0 >> 3) & 1, j0 = d0 & 7;
        bf16x4 vv = *(const bf16x4*)&c_lds[row * 132 + nh * 64 + d0];
        *(bf16x4*)&Kf[bhOff + (size_t)(((kvt * 4 + cc) * 64 + h2 * 32 + lk) * 8 + j0)] = vv;
      }
    }
  }
}

// ---------------- helpers ----------------
__device__ inline int pack_bf16(float lo, float hi) {
  bf16x2 v; v[0] = (bf16_t)lo; v[1] = (bf16_t)hi;
  return __builtin_bit_cast(int, v);
}
__device__ inline void permswap(int& a, int& b) {
  asm volatile("v_permlane32_swap_b32 %0, %1" : "+v"(a), "+v"(b));
}

// ---------------- causal flash attention, pair-split + ones-column l ----------------
// Round-17: l = P @ 1-vector via 2 extra MFMAs per tile (matrix pipe, idle)
// replacing the 16-add VALU sum tree + both l shuffles. 32x32 C/D layout makes
// every column identical -> lacc[r] IS row qr's sum, lane-local. l now sums
// the SAME bf16-rounded P that feeds PV (more consistent normalization).
// Rest frozen from r15 (84.9->sub-70us lineage).
__global__ __launch_bounds__(256, 4) void attn_fwd(const bf16_t* __restrict__ Q,
                                                   const bf16_t* __restrict__ Kf,
                                                   const bf16_t* __restrict__ Vf,
                                                   float* __restrict__ out) {
  __shared__ float o_sh[2][64][33];    // [grp][lane][r] pad 33 -> conflict-free
  __shared__ float m_sh[2][32];
  __shared__ float l_sh[2][32];

  const int tid  = threadIdx.x;
  const int wave = tid >> 6;
  const int lane = tid & 63;
  const int l31  = lane & 31;
  const int hi   = lane >> 5;

  const int f   = blockIdx.x;                  // 0..2047
  const int bh  = ((f & 7) << 3) | ((f >> 3) & 7);
  const int pr  = f >> 6;                      // 0..31
  const int grp = wave >> 1;                   // 0: chunk pr, 1: chunk 63-pr
  const int isWriter = wave & 1;
  const int chunk = grp ? (63 - pr) : pr;
  const int q0 = chunk * 32;
  const int n  = chunk + 1;                    // tiles in this chunk
  const int h  = (n + 1) >> 1;                 // merger gets [0,h), writer [h,n)
  const int j0 = isWriter ? h : 0;
  const int j1 = isWriter ? n : h;

  const bf16_t* Qp = Q  + (size_t)bh * T_SEQ * HD;
  const bf16_t* Kp = Kf + (size_t)bh * T_SEQ * HD;
  const bf16_t* Vp = Vf + (size_t)bh * T_SEQ * HD;
  float* op = out + (size_t)bh * T_SEQ * HD;

  // Q fragments (B-operand: col=lane&31, k=(lane>>5)*8+i)
  bf16x8 qf[4];
#pragma unroll
  for (int c = 0; c < 4; ++c)
    qf[c] = *(const bf16x8*)&Qp[(size_t)(q0 + l31) * HD + c * 16 + hi * 8];

  bf16x8 ones;
#pragma unroll
  for (int i = 0; i < 8; ++i) ones[i] = (bf16_t)1.0f;

  f32x16 o0 = {}, o1 = {}, lacc = {};
  float m_run = -INFINITY;

  if (j0 < j1) {
    // strength-reduced pointers: one add per tile, no per-load 64-bit mads
    const bf16_t* kp = Kp + (size_t)j0 * 2048 + lane * 8;
    const bf16_t* vp = Vp + (size_t)j0 * 2048 + lane * 8;
    bf16x8 kA[4], vA[4];
#pragma unroll
    for (int c = 0; c < 4; ++c) kA[c] = *(const bf16x8*)(kp + c * 512);
    kp += 2048;

    for (int j = j0; j < j1; ++j) {
      const int kv0 = j * 32;
      // V for THIS tile: issue now, consumed after softmax
#pragma unroll
      for (int idx = 0; idx < 4; ++idx) vA[idx] = *(const bf16x8*)(vp + idx * 512);
      vp += 2048;

      f32x16 st = {};
      __builtin_amdgcn_s_setprio(1);
#pragma unroll
      for (int c = 0; c < 4; ++c)
        st = __builtin_amdgcn_mfma_f32_32x32x16_bf16(kA[c], qf[c], st, 0, 0, 0);
      __builtin_amdgcn_s_setprio(0);

      // prefetch K for NEXT tile (wave-uniform branch)
      if (j + 1 < j1) {
#pragma unroll
        for (int c = 0; c < 4; ++c) kA[c] = *(const bf16x8*)(kp + c * 512);
        kp += 2048;
      }

      if (kv0 == q0) {   // diagonal tile
#pragma unroll
        for (int r = 0; r < 16; ++r) {
          const int koff = (r & 3) + 8 * (r >> 2) + 4 * hi;
          st[r] = (koff > l31) ? -INFINITY : st[r];
        }
      }
      // max3-fusable tree: 16 values via 7 max3 + 1 max
      const float t0 = fmaxf(fmaxf(st[0],  st[1]),  st[2]);
      const float t1 = fmaxf(fmaxf(st[3],  st[4]),  st[5]);
      const float t2 = fmaxf(fmaxf(st[6],  st[7]),  st[8]);
      const float t3 = fmaxf(fmaxf(st[9],  st[10]), st[11]);
      const float t4 = fmaxf(fmaxf(st[12], st[13]), st[14]);
      float pm = fmaxf(fmaxf(fmaxf(t0, t1), t2), fmaxf(fmaxf(t3, t4), st[15]));

      // defer-max (T13): rescale only when the local max grows past m_run+8.
      if (__any(!(pm <= m_run + 8.f))) {
        const float pm_full = fmaxf(pm, __shfl_xor(pm, 32));
        const float m_new = fmaxf(m_run, pm_full);
        const float alpha = fexp2(m_run - m_new);   // first tile: exp2(-inf)=0
        m_run = m_new;
#pragma unroll
        for (int r = 0; r < 16; ++r) {
          const int qr = (r & 3) + 8 * (r >> 2) + 4 * hi;
          const float av = __shfl(alpha, qr);
          o0[r] *= av; o1[r] *= av; lacc[r] *= av;
        }
      }

      float p[16];
#pragma unroll
      for (int r = 0; r < 16; ++r) p[r] = fexp2(st[r] - m_run);

      int a01 = pack_bf16(p[0],  p[1]),  a23 = pack_bf16(p[2],  p[3]);
      int b01 = pack_bf16(p[4],  p[5]),  b23 = pack_bf16(p[6],  p[7]);
      int c01 = pack_bf16(p[8],  p[9]),  c23 = pack_bf16(p[10], p[11]);
      int d01 = pack_bf16(p[12], p[13]), d23 = pack_bf16(p[14], p[15]);
      permswap(a01, b01); permswap(a23, b23);
      permswap(c01, d01); permswap(c23, d23);
      i32x4 w1 = {a01, a23, b01, b23};
      i32x4 w2 = {c01, c23, d01, d23};
      bf16x8 f1 = __builtin_bit_cast(bf16x8, w1);
      bf16x8 f2 = __builtin_bit_cast(bf16x8, w2);

      __builtin_amdgcn_s_setprio(1);
      lacc = __builtin_amdgcn_mfma_f32_32x32x16_bf16(f1, ones, lacc, 0, 0, 0);
      lacc = __builtin_amdgcn_mfma_f32_32x32x16_bf16(f2, ones, lacc, 0, 0, 0);
      o0 = __builtin_amdgcn_mfma_f32_32x32x16_bf16(f1, vA[0], o0, 0, 0, 0);
      o0 = __builtin_amdgcn_mfma_f32_32x32x16_bf16(f2, vA[1], o0, 0, 0, 0);
      o1 = __builtin_amdgcn_mfma_f32_32x32x16_bf16(f1, vA[2], o1, 0, 0, 0);
      o1 = __builtin_amdgcn_mfma_f32_32x32x16_bf16(f2, vA[3], o1, 0, 0, 0);
      __builtin_amdgcn_s_setprio(0);
    }
  }

  if (isWriter) {
#pragma unroll
    for (int r = 0; r < 16; ++r) {
      o_sh[grp][lane][r]      = o0[r];
      o_sh[grp][lane][16 + r] = o1[r];
    }
    if (lane < 32) m_sh[grp][lane] = m_run;
    if (l31 == 0) {   // lanes 0 and 32 cover all 32 rows across hi
#pragma unroll
      for (int r = 0; r < 16; ++r)
        l_sh[grp][(r & 3) + 8 * (r >> 2) + 4 * hi] = lacc[r];
    }
  }
  __syncthreads();
  if (!isWriter) {
    // flash-merge: m=max, o = oA*aA + oB*aB, l likewise; then divide & store.
#pragma unroll
    for (int r = 0; r < 16; ++r) {
      const int qr = (r & 3) + 8 * (r >> 2) + 4 * hi;
      const float mB = m_sh[grp][qr];
      const float lB = l_sh[grp][qr];
      const float mA = __shfl(m_run, qr);     // merger never empty -> finite
      const float lA = lacc[r];               // lane-local (all cols identical)
      const float mM = fmaxf(mA, mB);
      const float aA = fexp2(mA - mM);
      const float aB = fexp2(mB - mM);        // empty writer: exp2(-inf)=0
      const float li = 1.f / (lA * aA + lB * aB);
      const float x0 = (o0[r] * aA + o_sh[grp][lane][r]      * aB) * li;
      const float x1 = (o1[r] * aA + o_sh[grp][lane][16 + r] * aB) * li;
      op[(size_t)(q0 + qr) * HD + l31]      = x0;
      op[(size_t)(q0 + qr) * HD + 32 + l31] = x1;
    }
  }
}

extern "C" void kernel_launch(void* const* d_in, const int* in_sizes, int n_in,
                              void* d_out, int out_size, void* d_ws, size_t ws_size,
                              hipStream_t stream) {
  const float* x = (const float*)d_in[0];
  const float* W = (const float*)d_in[1];
  float* out = (float*)d_out;

  char* ws = (char*)d_ws;
  bf16_t* xb  = (bf16_t*)(ws);
  bf16_t* wb  = (bf16_t*)(ws + 16777216);
  bf16_t* Qb  = (bf16_t*)(ws + 16777216 + 6291456);
  bf16_t* Kfb = Qb + 8388608;
  bf16_t* Vfb = Kfb + 8388608;

  cvt_both<<<2048, 256, 0, stream>>>(x, xb, (M_TOT * D_MODEL) / 4,
                                     W, wb, (N_TOT * D_MODEL) / 4);

  dim3 ggrid(N_TOT / 128, M_TOT / 128);   // (24, 64) — r15 128x128 tiles
  qkv_gemm<<<ggrid, 256, 0, stream>>>(xb, wb, Qb, Kfb, Vfb);

  // 2048 blocks: f&7 = XCD (all blocks of a bh co-locate); f>>6 = pair index
  attn_fwd<<<2048, 256, 0, stream>>>(Qb, Kfb, Vfb, out);
}

// Round 18
// 134.730 us; speedup vs baseline: 1.2429x; 1.2429x over previous
//
#include <hip/hip_runtime.h>
#include <hip/hip_bf16.h>
#include <math.h>

#define D_MODEL 1024
#define N_HEAD  16
#define HD      64
#define B_SZ    4
#define T_SEQ   2048
#define M_TOT   (B_SZ * T_SEQ)   // 8192
#define N_TOT   (3 * D_MODEL)    // 3072

typedef __bf16 bf16_t;
typedef __bf16 bf16x8 __attribute__((ext_vector_type(8)));
typedef __bf16 bf16x4 __attribute__((ext_vector_type(4)));
typedef __bf16 bf16x2 __attribute__((ext_vector_type(2)));
typedef float  f32x4  __attribute__((ext_vector_type(4)));
typedef float  f32x16 __attribute__((ext_vector_type(16)));
typedef int    i32x4  __attribute__((ext_vector_type(4)));

// softmax scale folded with log2(e): scores end up in log2 domain -> exp2
#define Q_PRESCALE 0.18033688011112042f   // (1/8) * log2(e)

// raw v_exp_f32 (2^x): single instruction (r15 win).
__device__ inline float fexp2(float x) { return __builtin_amdgcn_exp2f(x); }

// ---------------- fused fp32 -> bf16 conversion (both inputs, one launch) ----------------
__global__ __launch_bounds__(256) void cvt_both(const float* __restrict__ x,
                                                bf16_t* __restrict__ xb, int n4x,
                                                const float* __restrict__ W,
                                                bf16_t* __restrict__ wb, int n4w) {
  int i = blockIdx.x * blockDim.x + threadIdx.x;
  int stride = gridDim.x * blockDim.x;
  const int ntot = n4x + n4w;
  for (; i < ntot; i += stride) {
    const float4* src = (i < n4x) ? &((const float4*)x)[i] : &((const float4*)W)[i - n4x];
    bf16x4* dst = (i < n4x) ? &((bf16x4*)xb)[i] : &((bf16x4*)wb)[i - n4x];
    float4 v = *src;
    bf16x4 o;
    o[0] = (bf16_t)v.x; o[1] = (bf16_t)v.y; o[2] = (bf16_t)v.z; o[3] = (bf16_t)v.w;
    *dst = o;
  }
}

// ---------------- QKV projection GEMM (bf16 MFMA, 128x128 tile) ----------------
// r15-exact (70us best measured): 3-buf counted-vmcnt pipeline + pre-swizzled
// staging + packed/LDS-transpose epilogue.
//  Kf[bh][t>>5][d>>4][(d>>3)&1][t&31][d&7]
//  Vf[bh][t>>5][(d>>5)*2+((t&31)>>4)][((t&31)>>3)&1][d&31][t&7]
__global__ __launch_bounds__(256) void qkv_gemm(const bf16_t* __restrict__ xb,
                                                const bf16_t* __restrict__ wb,
                                                bf16_t* __restrict__ Q,
                                                bf16_t* __restrict__ Kf,
                                                bf16_t* __restrict__ Vf) {
  __shared__ alignas(16) bf16_t smem[24576];   // 48 KB: staging; aliased as C-tile in epilogue
  bf16_t* a_lds = smem;                        // [3][4096]
  bf16_t* b_lds = smem + 12288;                // [3][4096]
  bf16_t* c_lds = smem;                        // [128][132] bf16 — epilogue only

  const int tid  = threadIdx.x;
  const int wave = tid >> 6;
  const int lane = tid & 63;
  const int bm = blockIdx.y * 128;
  const int bn = blockIdx.x * 128;
  const int sec = bn >> 10;                    // whole block in one section

  f32x4 acc[4][4] = {};

  const int sRow  = lane >> 2;
  const int sCol8 = (lane & 3) ^ ((lane >> 3) & 3);   // pre-swizzled global col8
  const int fr = lane & 15;
  const int fk = lane >> 4;
  const int wm = (wave >> 1) * 64;
  const int wn = (wave & 1) * 64;

  auto stage = [&](int buf, int kk) {
#pragma unroll
    for (int c = 0; c < 2; ++c) {
      const int chunk = wave * 2 + c;
      const bf16_t* gA = &xb[(size_t)(bm + chunk * 16 + sRow) * D_MODEL + kk + sCol8 * 8];
      __builtin_amdgcn_global_load_lds(
          (__attribute__((address_space(1))) void*)(void*)gA,
          (__attribute__((address_space(3))) void*)&a_lds[buf * 4096 + chunk * 512], 16, 0, 0);
      const bf16_t* gB = &wb[(size_t)(bn + chunk * 16 + sRow) * D_MODEL + kk + sCol8 * 8];
      __builtin_amdgcn_global_load_lds(
          (__attribute__((address_space(1))) void*)(void*)gB,
          (__attribute__((address_space(3))) void*)&b_lds[buf * 4096 + chunk * 512], 16, 0, 0);
    }
  };

  auto loadFrags = [&](int buf, bf16x8 af[4], bf16x8 bfr[4]) {
#pragma unroll
    for (int mt = 0; mt < 4; ++mt) {
      const int row = wm + mt * 16 + fr;
      af[mt] = *(const bf16x8*)&a_lds[buf * 4096 + row * 32 + (fk ^ ((fr >> 1) & 3)) * 8];
    }
#pragma unroll
    for (int nt = 0; nt < 4; ++nt) {
      const int row = wn + nt * 16 + fr;
      bfr[nt] = *(const bf16x8*)&b_lds[buf * 4096 + row * 32 + (fk ^ ((fr >> 1) & 3)) * 8];
    }
  };

  auto mfmaAll = [&](bf16x8 af[4], bf16x8 bfr[4]) {
    __builtin_amdgcn_s_setprio(1);
#pragma unroll
    for (int mt = 0; mt < 4; ++mt)
#pragma unroll
      for (int nt = 0; nt < 4; ++nt)
        acc[mt][nt] = __builtin_amdgcn_mfma_f32_16x16x32_bf16(af[mt], bfr[nt], acc[mt][nt], 0, 0, 0);
    __builtin_amdgcn_s_setprio(0);
  };

  stage(0, 0);
  stage(1, 32);
  int cur = 0;
  for (int t = 0; t < 31; ++t) {
    asm volatile("s_waitcnt vmcnt(4)" ::: "memory");
    __builtin_amdgcn_s_barrier();
    __builtin_amdgcn_sched_barrier(0);
    bf16x8 af[4], bfr[4];
    loadFrags(cur, af, bfr);
    if (t < 30) stage((t + 2) % 3, (t + 2) * 32);
    mfmaAll(af, bfr);
    cur = (cur + 1) % 3;
  }
  asm volatile("s_waitcnt vmcnt(0)" ::: "memory");
  __builtin_amdgcn_s_barrier();
  __builtin_amdgcn_sched_barrier(0);
  {
    bf16x8 af[4], bfr[4];
    loadFrags(cur, af, bfr);
    mfmaAll(af, bfr);
  }

  const int cRowBase = (lane >> 4) * 4;
  const int cCol     = lane & 15;

  if (sec == 2) {
    // ---- V: direct packed 8B stores ----
#pragma unroll
    for (int mt = 0; mt < 4; ++mt) {
#pragma unroll
      for (int nt = 0; nt < 4; ++nt) {
        const int hn = (bn & 1023) + wn + nt * 16 + cCol;
        const int h  = hn >> 6;
        const int d  = hn & 63;
        const int mbase = bm + wm + mt * 16 + cRowBase;
        const int b  = mbase >> 11;
        const int t0 = mbase & 2047;
        const int kvt = t0 >> 5, tt0 = t0 & 31;
        const int idx = (d >> 5) * 2 + (tt0 >> 4);
        const int h2  = (tt0 >> 3) & 1;
        const int j0  = tt0 & 7;
        bf16x4 pk;
        pk[0] = (bf16_t)acc[mt][nt][0]; pk[1] = (bf16_t)acc[mt][nt][1];
        pk[2] = (bf16_t)acc[mt][nt][2]; pk[3] = (bf16_t)acc[mt][nt][3];
        const size_t bhOff = (size_t)(b * N_HEAD + h) * (T_SEQ * HD);
        *(bf16x4*)&Vf[bhOff + (size_t)(((kvt * 4 + idx) * 64 + h2 * 32 + (d & 31)) * 8 + j0)] = pk;
      }
    }
  } else {
    // ---- Q/K: LDS transpose then contiguous 8B stores ----
    __syncthreads();
    const float qs = (sec == 0) ? Q_PRESCALE : 1.0f;
#pragma unroll
    for (int mt = 0; mt < 4; ++mt)
#pragma unroll
      for (int nt = 0; nt < 4; ++nt)
#pragma unroll
        for (int r = 0; r < 4; ++r) {
          const int mloc = wm + mt * 16 + cRowBase + r;
          const int nloc = wn + nt * 16 + cCol;
          c_lds[mloc * 132 + nloc] = (bf16_t)(acc[mt][nt][r] * qs);
        }
    __syncthreads();

    const int row = tid >> 1;
    const int nh  = tid & 1;
    const int m = bm + row;
    const int b = m >> 11, t = m & 2047;
    const int h = ((bn & 1023) + nh * 64) >> 6;
    const size_t bhOff = (size_t)(b * N_HEAD + h) * (T_SEQ * HD);

    if (sec == 0) {
      bf16_t* qp = Q + bhOff + (size_t)t * HD;
#pragma unroll
      for (int o = 0; o < 16; ++o) {
        bf16x4 vv = *(const bf16x4*)&c_lds[row * 132 + nh * 64 + o * 4];
        *(bf16x4*)&qp[o * 4] = vv;
      }
    } else {
      const int kvt = t >> 5, lk = t & 31;
#pragma unroll
      for (int o = 0; o < 16; ++o) {
        const int d0 = o * 4;
        const int cc = d0 >> 4, h2 = (d0 >> 3) & 1, j0 = d0 & 7;
        bf16x4 vv = *(const bf16x4*)&c_lds[row * 132 + nh * 64 + d0];
        *(bf16x4*)&Kf[bhOff + (size_t)(((kvt * 4 + cc) * 64 + h2 * 32 + lk) * 8 + j0)] = vv;
      }
    }
  }
}

// ---------------- helpers ----------------
__device__ inline int pack_bf16(float lo, float hi) {
  bf16x2 v; v[0] = (bf16_t)lo; v[1] = (bf16_t)hi;
  return __builtin_bit_cast(int, v);
}
__device__ inline void permswap(int& a, int& b) {
  asm volatile("v_permlane32_swap_b32 %0, %1" : "+v"(a), "+v"(b));
}

// ---------------- causal flash attention (r15-exact; r17 ones-trick reverted:
// +lacc spilled to scratch — WRITE_SIZE doubled, 55->107us) ----------------
__global__ __launch_bounds__(256, 4) void attn_fwd(const bf16_t* __restrict__ Q,
                                                   const bf16_t* __restrict__ Kf,
                                                   const bf16_t* __restrict__ Vf,
                                                   float* __restrict__ out) {
  __shared__ float o_sh[2][64][33];    // [grp][lane][r] pad 33 -> conflict-free
  __shared__ float m_sh[2][32];
  __shared__ float l_sh[2][32];

  const int tid  = threadIdx.x;
  const int wave = tid >> 6;
  const int lane = tid & 63;
  const int l31  = lane & 31;
  const int hi   = lane >> 5;

  const int f   = blockIdx.x;                  // 0..2047
  const int bh  = ((f & 7) << 3) | ((f >> 3) & 7);
  const int pr  = f >> 6;                      // 0..31
  const int grp = wave >> 1;                   // 0: chunk pr, 1: chunk 63-pr
  const int isWriter = wave & 1;
  const int chunk = grp ? (63 - pr) : pr;
  const int q0 = chunk * 32;
  const int n  = chunk + 1;                    // tiles in this chunk
  const int h  = (n + 1) >> 1;                 // merger gets [0,h), writer [h,n)
  const int j0 = isWriter ? h : 0;
  const int j1 = isWriter ? n : h;

  const bf16_t* Qp = Q  + (size_t)bh * T_SEQ * HD;
  const bf16_t* Kp = Kf + (size_t)bh * T_SEQ * HD;
  const bf16_t* Vp = Vf + (size_t)bh * T_SEQ * HD;
  float* op = out + (size_t)bh * T_SEQ * HD;

  // Q fragments (B-operand: col=lane&31, k=(lane>>5)*8+i)
  bf16x8 qf[4];
#pragma unroll
  for (int c = 0; c < 4; ++c)
    qf[c] = *(const bf16x8*)&Qp[(size_t)(q0 + l31) * HD + c * 16 + hi * 8];

  f32x16 o0 = {}, o1 = {};
  float m_run = -INFINITY;
  float l_run = 0.f;          // per-lane HALF-row partial sum

  if (j0 < j1) {
    // strength-reduced pointers: one add per tile, no per-load 64-bit mads
    const bf16_t* kp = Kp + (size_t)j0 * 2048 + lane * 8;
    const bf16_t* vp = Vp + (size_t)j0 * 2048 + lane * 8;
    bf16x8 kA[4], vA[4];
#pragma unroll
    for (int c = 0; c < 4; ++c) kA[c] = *(const bf16x8*)(kp + c * 512);
    kp += 2048;

    for (int j = j0; j < j1; ++j) {
      const int kv0 = j * 32;
      // V for THIS tile: issue now, consumed after softmax
#pragma unroll
      for (int idx = 0; idx < 4; ++idx) vA[idx] = *(const bf16x8*)(vp + idx * 512);
      vp += 2048;

      f32x16 st = {};
      __builtin_amdgcn_s_setprio(1);
#pragma unroll
      for (int c = 0; c < 4; ++c)
        st = __builtin_amdgcn_mfma_f32_32x32x16_bf16(kA[c], qf[c], st, 0, 0, 0);
      __builtin_amdgcn_s_setprio(0);

      // prefetch K for NEXT tile (wave-uniform branch)
      if (j + 1 < j1) {
#pragma unroll
        for (int c = 0; c < 4; ++c) kA[c] = *(const bf16x8*)(kp + c * 512);
        kp += 2048;
      }

      if (kv0 == q0) {   // diagonal tile
#pragma unroll
        for (int r = 0; r < 16; ++r) {
          const int koff = (r & 3) + 8 * (r >> 2) + 4 * hi;
          st[r] = (koff > l31) ? -INFINITY : st[r];
        }
      }
      // max3-fusable tree: 16 values via 7 max3 + 1 max
      const float t0 = fmaxf(fmaxf(st[0],  st[1]),  st[2]);
      const float t1 = fmaxf(fmaxf(st[3],  st[4]),  st[5]);
      const float t2 = fmaxf(fmaxf(st[6],  st[7]),  st[8]);
      const float t3 = fmaxf(fmaxf(st[9],  st[10]), st[11]);
      const float t4 = fmaxf(fmaxf(st[12], st[13]), st[14]);
      float pm = fmaxf(fmaxf(fmaxf(t0, t1), t2), fmaxf(fmaxf(t3, t4), st[15]));

      // defer-max (T13): rescale only when the local max grows past m_run+8.
      if (__any(!(pm <= m_run + 8.f))) {
        const float pm_full = fmaxf(pm, __shfl_xor(pm, 32));
        const float m_new = fmaxf(m_run, pm_full);
        const float alpha = fexp2(m_run - m_new);   // first tile: exp2(-inf)=0
        m_run = m_new;
        l_run *= alpha;
#pragma unroll
        for (int r = 0; r < 16; ++r) {
          const int qr = (r & 3) + 8 * (r >> 2) + 4 * hi;
          const float av = __shfl(alpha, qr);
          o0[r] *= av; o1[r] *= av;
        }
      }

      float p[16];
#pragma unroll
      for (int r = 0; r < 16; ++r) p[r] = fexp2(st[r] - m_run);
      float s0 = (p[0] + p[1]) + (p[2] + p[3]);
      float s1 = (p[4] + p[5]) + (p[6] + p[7]);
      float s2 = (p[8] + p[9]) + (p[10] + p[11]);
      float s3 = (p[12] + p[13]) + (p[14] + p[15]);
      l_run += (s0 + s1) + (s2 + s3);

      int a01 = pack_bf16(p[0],  p[1]),  a23 = pack_bf16(p[2],  p[3]);
      int b01 = pack_bf16(p[4],  p[5]),  b23 = pack_bf16(p[6],  p[7]);
      int c01 = pack_bf16(p[8],  p[9]),  c23 = pack_bf16(p[10], p[11]);
      int d01 = pack_bf16(p[12], p[13]), d23 = pack_bf16(p[14], p[15]);
      permswap(a01, b01); permswap(a23, b23);
      permswap(c01, d01); permswap(c23, d23);
      i32x4 w1 = {a01, a23, b01, b23};
      i32x4 w2 = {c01, c23, d01, d23};
      bf16x8 f1 = __builtin_bit_cast(bf16x8, w1);
      bf16x8 f2 = __builtin_bit_cast(bf16x8, w2);

      __builtin_amdgcn_s_setprio(1);
      o0 = __builtin_amdgcn_mfma_f32_32x32x16_bf16(f1, vA[0], o0, 0, 0, 0);
      o0 = __builtin_amdgcn_mfma_f32_32x32x16_bf16(f2, vA[1], o0, 0, 0, 0);
      o1 = __builtin_amdgcn_mfma_f32_32x32x16_bf16(f1, vA[2], o1, 0, 0, 0);
      o1 = __builtin_amdgcn_mfma_f32_32x32x16_bf16(f2, vA[3], o1, 0, 0, 0);
      __builtin_amdgcn_s_setprio(0);
    }
  }

  const float l_comb = l_run + __shfl_xor(l_run, 32);   // full-row partial sum

  if (isWriter) {
#pragma unroll
    for (int r = 0; r < 16; ++r) {
      o_sh[grp][lane][r]      = o0[r];
      o_sh[grp][lane][16 + r] = o1[r];
    }
    if (lane < 32) {
      m_sh[grp][lane] = m_run;
      l_sh[grp][lane] = l_comb;
    }
  }
  __syncthreads();
  if (!isWriter) {
    // flash-merge: m=max, o = oA*aA + oB*aB, l likewise; then divide & store.
#pragma unroll
    for (int r = 0; r < 16; ++r) {
      const int qr = (r & 3) + 8 * (r >> 2) + 4 * hi;
      const float mB = m_sh[grp][qr];
      const float lB = l_sh[grp][qr];
      const float mA = __shfl(m_run, qr);     // merger never empty -> finite
      const float lA = __shfl(l_comb, qr);
      const float mM = fmaxf(mA, mB);
      const float aA = fexp2(mA - mM);
      const float aB = fexp2(mB - mM);        // empty writer: exp2(-inf)=0
      const float li = 1.f / (lA * aA + lB * aB);
      const float x0 = (o0[r] * aA + o_sh[grp][lane][r]      * aB) * li;
      const float x1 = (o1[r] * aA + o_sh[grp][lane][16 + r] * aB) * li;
      op[(size_t)(q0 + qr) * HD + l31]      = x0;
      op[(size_t)(q0 + qr) * HD + 32 + l31] = x1;
    }
  }
}

extern "C" void kernel_launch(void* const* d_in, const int* in_sizes, int n_in,
                              void* d_out, int out_size, void* d_ws, size_t ws_size,
                              hipStream_t stream) {
  const float* x = (const float*)d_in[0];
  const float* W = (const float*)d_in[1];
  float* out = (float*)d_out;

  char* ws = (char*)d_ws;
  bf16_t* xb  = (bf16_t*)(ws);
  bf16_t* wb  = (bf16_t*)(ws + 16777216);
  bf16_t* Qb  = (bf16_t*)(ws + 16777216 + 6291456);
  bf16_t* Kfb = Qb + 8388608;
  bf16_t* Vfb = Kfb + 8388608;

  cvt_both<<<2048, 256, 0, stream>>>(x, xb, (M_TOT * D_MODEL) / 4,
                                     W, wb, (N_TOT * D_MODEL) / 4);

  dim3 ggrid(N_TOT / 128, M_TOT / 128);   // (24, 64) — r15 128x128 tiles
  qkv_gemm<<<ggrid, 256, 0, stream>>>(xb, wb, Qb, Kfb, Vfb);

  // 2048 blocks: f&7 = XCD (all blocks of a bh co-locate); f>>6 = pair index
  attn_fwd<<<2048, 256, 0, stream>>>(Qb, Kfb, Vfb, out);
}